// Round 3
// baseline (578.644 us; speedup 1.0000x reference)
//
#include <hip/hip_runtime.h>
#include <stdint.h>

using short8  = __attribute__((ext_vector_type(8))) short;   // 8 x bf16 (4 VGPRs)
using floatx4 = __attribute__((ext_vector_type(4))) float;   // MFMA acc
using u16 = unsigned short;
using u32 = unsigned int;

#define MFMA16(A,B,C) __builtin_amdgcn_mfma_f32_16x16x32_bf16((A),(B),(C),0,0,0)

static __device__ __forceinline__ u16 f2bf(float f) {
  u32 u = __float_as_uint(f);
  u += 0x7fffu + ((u >> 16) & 1u);   // RNE
  return (u16)(u >> 16);
}
static __device__ __forceinline__ u32 pack2(float a, float b) {
  return (u32)f2bf(a) | ((u32)f2bf(b) << 16);
}

// CK-style global->LDS direct copy, 16B per lane. LDS dest must be wave-uniform
// base (HW adds lane*16); global src is per-lane (carries the swizzle).
static __device__ __forceinline__ void gl2lds16(const void* g, void* l) {
  auto gp = reinterpret_cast<__attribute__((address_space(1))) u32*>(
      reinterpret_cast<uintptr_t>(g));
  auto lp = reinterpret_cast<__attribute__((address_space(3))) u32*>(
      reinterpret_cast<uintptr_t>(l));
  __builtin_amdgcn_global_load_lds(gp, lp, 16, 0, 0);
}

// ---------------- prep: fp32 -> bf16 convert ----------------
__global__ __launch_bounds__(256) void cvt_x(const float* __restrict__ x,
                                             u16* __restrict__ xb) {
  size_t i = ((size_t)blockIdx.x * 256 + threadIdx.x) * 8;
  float4 a = *(const float4*)&x[i];
  float4 b = *(const float4*)&x[i + 4];
  uint4 pk = make_uint4(pack2(a.x, a.y), pack2(a.z, a.w),
                        pack2(b.x, b.y), pack2(b.z, b.w));
  *(uint4*)&xb[i] = pk;
}

// W[K][N] fp32 -> Wt[N][K] bf16 (tiled 64x64 transpose through LDS)
__global__ __launch_bounds__(256) void tr_cvt(const float* __restrict__ W,
                                              u16* __restrict__ Wt,
                                              int K, int N) {
  __shared__ u16 t[64][72];   // +8 pad
  const int tid = threadIdx.x;
  const int n0 = blockIdx.x * 64, k0 = blockIdx.y * 64;
#pragma unroll
  for (int i = 0; i < 4; ++i) {
    int c = i * 256 + tid;
    int r = c >> 4, co = (c & 15) * 4;
    float4 v = *(const float4*)&W[(size_t)(k0 + r) * N + n0 + co];
    uint2 pk; pk.x = pack2(v.x, v.y); pk.y = pack2(v.z, v.w);
    *(uint2*)&t[r][co] = pk;
  }
  __syncthreads();
#pragma unroll
  for (int i = 0; i < 2; ++i) {
    int c = i * 256 + tid;
    int n = c >> 3, ko = (c & 7) * 8;
    u16 o[8];
#pragma unroll
    for (int j = 0; j < 8; ++j) o[j] = t[ko + j][n];
    uint4 pk = make_uint4((u32)o[0] | ((u32)o[1] << 16), (u32)o[2] | ((u32)o[3] << 16),
                          (u32)o[4] | ((u32)o[5] << 16), (u32)o[6] | ((u32)o[7] << 16));
    *(uint4*)&Wt[(size_t)(n0 + n) * K + k0 + ko] = pk;
  }
}

// ---------------- GEMM: A[M][K] bf16 x Bt[N][K] bf16 ----------------
// 128x128 tile, BK=64, 4 waves (2x2), each 64x64. Double-buffered LDS via
// global_load_lds(16B) with pre-swizzled global source (XOR chunk swizzle).
// MODE 0: epilogue routes QKV (Q scaled by SCALE*log2e, V transposed).
// MODE 1: fp32 + bias -> d_out.
template <int MODE>
__global__ __launch_bounds__(256)
void gemm_bt(const u16* __restrict__ A, const u16* __restrict__ Bt, int Kd,
             const float* __restrict__ bias, float* __restrict__ outF,
             u16* __restrict__ Qo, u16* __restrict__ Ko, u16* __restrict__ Vto) {
  __shared__ __align__(16) u16 lA[2][128 * 64];
  __shared__ __align__(16) u16 lB[2][128 * 64];
  const int tid = threadIdx.x;
  const int l = tid & 63, w = tid >> 6;
  const int g = l >> 4, ll = l & 15, l7 = l & 7, rl = l >> 3;
  const int mt = blockIdx.x, nt = blockIdx.y;
  const int wr = w >> 1, wc = w & 1;
  const int swz = ((l7 ^ rl) << 4);  // inverse-swizzle on the global source

  const char* srcA = (const char*)(A + (size_t)(mt * 128 + w * 32 + rl) * Kd) + swz;
  const char* srcB = (const char*)(Bt + (size_t)(nt * 128 + w * 32 + rl) * Kd) + swz;
  const size_t rstep = (size_t)8 * Kd * 2;

  floatx4 acc[4][4];
#pragma unroll
  for (int i = 0; i < 4; ++i)
#pragma unroll
    for (int j = 0; j < 4; ++j) acc[i][j] = floatx4{0.f, 0.f, 0.f, 0.f};

  const int NT = Kd >> 6;
  auto stage = [&](int t, int buf) {
    const char* a = srcA + (size_t)t * 128;
    const char* b = srcB + (size_t)t * 128;
    char* la = (char*)&lA[buf][0] + w * 4096;
    char* lb = (char*)&lB[buf][0] + w * 4096;
#pragma unroll
    for (int j = 0; j < 4; ++j) {
      gl2lds16(a + j * rstep, la + j * 1024);
      gl2lds16(b + j * rstep, lb + j * 1024);
    }
  };

  stage(0, 0);
  int cur = 0;
  for (int t = 0; t < NT; ++t) {
    __syncthreads();                       // drains vmcnt then barrier
    if (t + 1 < NT) stage(t + 1, cur ^ 1); // prefetch overlaps compute
    const u16* la = &lA[cur][0];
    const u16* lb = &lB[cur][0];
#pragma unroll
    for (int ks = 0; ks < 2; ++ks) {
      short8 af[4], bfr[4];
#pragma unroll
      for (int mi = 0; mi < 4; ++mi) {
        int row = wr * 64 + mi * 16 + ll;
        af[mi] = *(const short8*)&la[row * 64 + ((ks * 32 + g * 8) ^ (l7 * 8))];
      }
#pragma unroll
      for (int ni = 0; ni < 4; ++ni) {
        int row = wc * 64 + ni * 16 + ll;
        bfr[ni] = *(const short8*)&lb[row * 64 + ((ks * 32 + g * 8) ^ (l7 * 8))];
      }
#pragma unroll
      for (int mi = 0; mi < 4; ++mi)
#pragma unroll
        for (int ni = 0; ni < 4; ++ni)
          acc[mi][ni] = MFMA16(af[mi], bfr[ni], acc[mi][ni]);
    }
    cur ^= 1;
  }

  if (MODE == 0) {
    const float QS = 0.18033688011112042f;  // 1/8 * log2(e)
#pragma unroll
    for (int ni = 0; ni < 4; ++ni) {
      int np = nt * 128 + wc * 64 + ni * 16 + ll;
      int tsel = np >> 10, hh = (np >> 6) & 15, dd = np & 63;
      float bv = bias[np];
#pragma unroll
      for (int mi = 0; mi < 4; ++mi) {
        int n0r = mt * 128 + wr * 64 + mi * 16 + g * 4;
        floatx4 v = acc[mi][ni];
        if (tsel == 0) {
#pragma unroll
          for (int i = 0; i < 4; ++i)
            Qo[((size_t)hh * 4096 + n0r + i) * 64 + dd] = f2bf((v[i] + bv) * QS);
        } else if (tsel == 1) {
#pragma unroll
          for (int i = 0; i < 4; ++i)
            Ko[((size_t)hh * 4096 + n0r + i) * 64 + dd] = f2bf(v[i] + bv);
        } else {  // V transposed: Vt[h][d][n]
          uint2 pk; pk.x = pack2(v[0] + bv, v[1] + bv); pk.y = pack2(v[2] + bv, v[3] + bv);
          *(uint2*)&Vto[((size_t)hh * 64 + dd) * 4096 + n0r] = pk;
        }
      }
    }
  } else {
#pragma unroll
    for (int ni = 0; ni < 4; ++ni) {
      int col = nt * 128 + wc * 64 + ni * 16 + ll;
      float bv = bias[col];
#pragma unroll
      for (int mi = 0; mi < 4; ++mi) {
        int r0 = mt * 128 + wr * 64 + mi * 16 + g * 4;
#pragma unroll
        for (int i = 0; i < 4; ++i)
          outF[(size_t)(r0 + i) * 1024 + col] = acc[mi][ni][i] + bv;
      }
    }
  }
}

// ---------------- flash attention ----------------
// grid: 1024 blocks (flat), 4 waves/block, wave owns 16 q-rows.
// Block decode groups each head's 64 blocks onto ONE XCD (bid%8 = XCD):
// 2 heads/XCD -> K/V working set 2 MB -> L2-resident.
// Swapped QK^T: S^T = mfma(K, Q): lane holds 32 key-scores of ONE q-row
// (softmax reduce = in-reg + shfl_xor 16/32, all 64 lanes busy).
// P goes through per-wave swizzled LDS; PV computes O^T = mfma(V^T, P^T).
// K/V read direct from global (L2-resident; staging would be overhead).
// __launch_bounds__(256,4): cap VGPR at 128 -> 4 waves/SIMD.
__global__ __launch_bounds__(256, 4)
void attn_kernel(const u16* __restrict__ Qb, const u16* __restrict__ Kb,
                 const u16* __restrict__ Vt, u16* __restrict__ aout) {
  __shared__ __align__(16) char plds[4 * 4096];
  const int tid = threadIdx.x, l = tid & 63, w = tid >> 6;
  const int g = l >> 4, ll = l & 15;
  const int l7s = (ll & 7) << 4;       // row-derived XOR swizzle (bytes)
  const int bid = blockIdx.x;
  const int h = (bid & 7) * 2 + ((bid >> 3) & 1);
  const int qb = bid >> 4;
  const int q0 = qb * 64 + w * 16;
  const u16* Qh = Qb + (size_t)h * 4096 * 64;
  const u16* Kh = Kb + (size_t)h * 4096 * 64;
  const u16* Vh = Vt + (size_t)h * 64 * 4096;
  char* myp = plds + w * 4096;

  short8 qf[2];
#pragma unroll
  for (int ks = 0; ks < 2; ++ks)
    qf[ks] = *(const short8*)&Qh[(size_t)(q0 + ll) * 64 + ks * 32 + g * 8];

  float m = -1e30f, lsum = 0.f;
  floatx4 o[4];
#pragma unroll
  for (int fd = 0; fd < 4; ++fd) o[fd] = floatx4{0.f, 0.f, 0.f, 0.f};

  for (int kt = 0; kt < 32; ++kt) {
    const u16* Kt = Kh + (size_t)kt * 128 * 64;
    floatx4 s[8];
#pragma unroll
    for (int fr = 0; fr < 8; ++fr) s[fr] = floatx4{0.f, 0.f, 0.f, 0.f};

#pragma unroll
    for (int ks = 0; ks < 2; ++ks) {
      short8 kf[8];
#pragma unroll
      for (int fr = 0; fr < 8; ++fr)
        kf[fr] = *(const short8*)&Kt[(size_t)(fr * 16 + ll) * 64 + ks * 32 + g * 8];
#pragma unroll
      for (int fr = 0; fr < 8; ++fr)
        s[fr] = MFMA16(kf[fr], qf[ks], s[fr]);
    }

    // online softmax (base-2; scale folded into Q)
    float tm = -1e30f;
#pragma unroll
    for (int fr = 0; fr < 8; ++fr)
#pragma unroll
      for (int i = 0; i < 4; ++i) tm = fmaxf(tm, s[fr][i]);
    tm = fmaxf(tm, __shfl_xor(tm, 16));
    tm = fmaxf(tm, __shfl_xor(tm, 32));
    float mn = fmaxf(m, tm);
    float al = __builtin_amdgcn_exp2f(m - mn);
    float rs = 0.f;
#pragma unroll
    for (int fr = 0; fr < 8; ++fr)
#pragma unroll
      for (int i = 0; i < 4; ++i) {
        float p = __builtin_amdgcn_exp2f(s[fr][i] - mn);
        s[fr][i] = p;
        rs += p;
      }
    rs += __shfl_xor(rs, 16);
    rs += __shfl_xor(rs, 32);
    lsum = lsum * al + rs;
    m = mn;
#pragma unroll
    for (int fd = 0; fd < 4; ++fd) o[fd] *= al;

    // P -> LDS as [16 q][128 key] bf16, XOR-swizzled (same involution on read)
    {
      char* rowp = myp + ll * 256;
#pragma unroll
      for (int fr = 0; fr < 8; ++fr) {
        uint2 pk;
        pk.x = pack2(s[fr][0], s[fr][1]);
        pk.y = pack2(s[fr][2], s[fr][3]);
        *(uint2*)(rowp + ((fr * 32 + g * 8) ^ l7s)) = pk;
      }
    }

    // PV: O^T += V^T x P^T
#pragma unroll
    for (int ks2 = 0; ks2 < 4; ++ks2) {
      short8 vf[4];
#pragma unroll
      for (int fd = 0; fd < 4; ++fd)
        vf[fd] = *(const short8*)&Vh[(size_t)(fd * 16 + ll) * 4096 + kt * 128 + ks2 * 32 + g * 8];
      short8 pf = *(const short8*)(myp + ll * 256 + ((ks2 * 64 + g * 16) ^ l7s));
#pragma unroll
      for (int fd = 0; fd < 4; ++fd)
        o[fd] = MFMA16(vf[fd], pf, o[fd]);
    }
  }

  // normalize + write attn_out[n][h*64+d] bf16
  {
    float inv = 1.f / lsum;
    int n = q0 + ll;
#pragma unroll
    for (int fd = 0; fd < 4; ++fd) {
      uint2 pk;
      pk.x = pack2(o[fd][0] * inv, o[fd][1] * inv);
      pk.y = pack2(o[fd][2] * inv, o[fd][3] * inv);
      *(uint2*)&aout[(size_t)n * 1024 + h * 64 + fd * 16 + g * 4] = pk;
    }
  }
}

extern "C" void kernel_launch(void* const* d_in, const int* in_sizes, int n_in,
                              void* d_out, int out_size, void* d_ws, size_t ws_size,
                              hipStream_t stream) {
  const float* x    = (const float*)d_in[0];
  const float* Wqkv = (const float*)d_in[1];
  const float* bqkv = (const float*)d_in[2];
  const float* Wout = (const float*)d_in[3];
  const float* bout = (const float*)d_in[4];
  float* out = (float*)d_out;

  // d_ws usage: 24 MB total (defensive — ws_size is harness-chosen).
  u16* ws    = (u16*)d_ws;
  u16* xb    = ws;                            // 4M u16 = 8 MB (reused as aout)
  u16* wqkvT = xb + (size_t)4096 * 1024;      // 6 MB
  u16* woutT = wqkvT + (size_t)3072 * 1024;   // 2 MB
  u16* Vt    = woutT + (size_t)1024 * 1024;   // 8 MB
  u16* aout  = xb;                            // alias: xb dead after gemm<0>

  // Q and K live in d_out (16 MB fp32 buffer; holds exactly 2 x 8 MB bf16).
  // Both are dead before gemm<1> rewrites d_out in full.
  u16* Qb = (u16*)d_out;                      // 8 MB
  u16* Kb = Qb + (size_t)16 * 4096 * 64;      // 8 MB

  cvt_x<<<2048, 256, 0, stream>>>(x, xb);
  tr_cvt<<<dim3(48, 16), 256, 0, stream>>>(Wqkv, wqkvT, 1024, 3072);
  tr_cvt<<<dim3(16, 16), 256, 0, stream>>>(Wout, woutT, 1024, 1024);
  gemm_bt<0><<<dim3(32, 24), 256, 0, stream>>>(xb, wqkvT, 1024, bqkv, nullptr, Qb, Kb, Vt);
  attn_kernel<<<1024, 256, 0, stream>>>(Qb, Kb, Vt, aout);
  gemm_bt<1><<<dim3(32, 8), 256, 0, stream>>>(aout, woutT, 1024, bout, out,
                                              nullptr, nullptr, nullptr);
}

// Round 4
// 257.791 us; speedup vs baseline: 2.2446x; 2.2446x over previous
//
#include <hip/hip_runtime.h>
#include <stdint.h>

using short8  = __attribute__((ext_vector_type(8))) short;   // 8 x bf16 (4 VGPRs)
using floatx4 = __attribute__((ext_vector_type(4))) float;   // MFMA acc
using u16 = unsigned short;
using u32 = unsigned int;

#define MFMA16(A,B,C) __builtin_amdgcn_mfma_f32_16x16x32_bf16((A),(B),(C),0,0,0)

static __device__ __forceinline__ u16 f2bf(float f) {
  u32 u = __float_as_uint(f);
  u += 0x7fffu + ((u >> 16) & 1u);   // RNE
  return (u16)(u >> 16);
}
static __device__ __forceinline__ u32 pack2(float a, float b) {
  return (u32)f2bf(a) | ((u32)f2bf(b) << 16);
}

// CK-style global->LDS direct copy, 16B per lane. LDS dest must be wave-uniform
// base (HW adds lane*16); global src is per-lane (carries the swizzle).
static __device__ __forceinline__ void gl2lds16(const void* g, void* l) {
  auto gp = reinterpret_cast<__attribute__((address_space(1))) u32*>(
      reinterpret_cast<uintptr_t>(g));
  auto lp = reinterpret_cast<__attribute__((address_space(3))) u32*>(
      reinterpret_cast<uintptr_t>(l));
  __builtin_amdgcn_global_load_lds(gp, lp, 16, 0, 0);
}

// ---------------- prep: fp32 -> bf16 convert ----------------
__global__ __launch_bounds__(256) void cvt_x(const float* __restrict__ x,
                                             u16* __restrict__ xb) {
  size_t i = ((size_t)blockIdx.x * 256 + threadIdx.x) * 8;
  float4 a = *(const float4*)&x[i];
  float4 b = *(const float4*)&x[i + 4];
  uint4 pk = make_uint4(pack2(a.x, a.y), pack2(a.z, a.w),
                        pack2(b.x, b.y), pack2(b.z, b.w));
  *(uint4*)&xb[i] = pk;
}

// W[K][N] fp32 -> Wt[N][K] bf16 (tiled 64x64 transpose through LDS)
__global__ __launch_bounds__(256) void tr_cvt(const float* __restrict__ W,
                                              u16* __restrict__ Wt,
                                              int K, int N) {
  __shared__ u16 t[64][72];   // +8 pad
  const int tid = threadIdx.x;
  const int n0 = blockIdx.x * 64, k0 = blockIdx.y * 64;
#pragma unroll
  for (int i = 0; i < 4; ++i) {
    int c = i * 256 + tid;
    int r = c >> 4, co = (c & 15) * 4;
    float4 v = *(const float4*)&W[(size_t)(k0 + r) * N + n0 + co];
    uint2 pk; pk.x = pack2(v.x, v.y); pk.y = pack2(v.z, v.w);
    *(uint2*)&t[r][co] = pk;
  }
  __syncthreads();
#pragma unroll
  for (int i = 0; i < 2; ++i) {
    int c = i * 256 + tid;
    int n = c >> 3, ko = (c & 7) * 8;
    u16 o[8];
#pragma unroll
    for (int j = 0; j < 8; ++j) o[j] = t[ko + j][n];
    uint4 pk = make_uint4((u32)o[0] | ((u32)o[1] << 16), (u32)o[2] | ((u32)o[3] << 16),
                          (u32)o[4] | ((u32)o[5] << 16), (u32)o[6] | ((u32)o[7] << 16));
    *(uint4*)&Wt[(size_t)(n0 + n) * K + k0 + ko] = pk;
  }
}

// ---------------- GEMM: A[M][K] bf16 x Bt[N][K] bf16 ----------------
// 128x128 tile, BK=64, 4 waves (2x2), each 64x64. Double-buffered LDS via
// global_load_lds(16B) with pre-swizzled global source (XOR chunk swizzle).
// MODE 0: epilogue routes QKV (Q scaled by SCALE*log2e, V transposed).
// MODE 1: fp32 + bias -> d_out.
template <int MODE>
__global__ __launch_bounds__(256)
void gemm_bt(const u16* __restrict__ A, const u16* __restrict__ Bt, int Kd,
             const float* __restrict__ bias, float* __restrict__ outF,
             u16* __restrict__ Qo, u16* __restrict__ Ko, u16* __restrict__ Vto) {
  __shared__ __align__(16) u16 lA[2][128 * 64];
  __shared__ __align__(16) u16 lB[2][128 * 64];
  const int tid = threadIdx.x;
  const int l = tid & 63, w = tid >> 6;
  const int g = l >> 4, ll = l & 15, l7 = l & 7, rl = l >> 3;
  const int mt = blockIdx.x, nt = blockIdx.y;
  const int wr = w >> 1, wc = w & 1;
  const int swz = ((l7 ^ rl) << 4);  // inverse-swizzle on the global source

  const char* srcA = (const char*)(A + (size_t)(mt * 128 + w * 32 + rl) * Kd) + swz;
  const char* srcB = (const char*)(Bt + (size_t)(nt * 128 + w * 32 + rl) * Kd) + swz;
  const size_t rstep = (size_t)8 * Kd * 2;

  floatx4 acc[4][4];
#pragma unroll
  for (int i = 0; i < 4; ++i)
#pragma unroll
    for (int j = 0; j < 4; ++j) acc[i][j] = floatx4{0.f, 0.f, 0.f, 0.f};

  const int NT = Kd >> 6;
  auto stage = [&](int t, int buf) {
    const char* a = srcA + (size_t)t * 128;
    const char* b = srcB + (size_t)t * 128;
    char* la = (char*)&lA[buf][0] + w * 4096;
    char* lb = (char*)&lB[buf][0] + w * 4096;
#pragma unroll
    for (int j = 0; j < 4; ++j) {
      gl2lds16(a + j * rstep, la + j * 1024);
      gl2lds16(b + j * rstep, lb + j * 1024);
    }
  };

  stage(0, 0);
  int cur = 0;
  for (int t = 0; t < NT; ++t) {
    __syncthreads();                       // drains vmcnt then barrier
    if (t + 1 < NT) stage(t + 1, cur ^ 1); // prefetch overlaps compute
    const u16* la = &lA[cur][0];
    const u16* lb = &lB[cur][0];
#pragma unroll
    for (int ks = 0; ks < 2; ++ks) {
      short8 af[4], bfr[4];
#pragma unroll
      for (int mi = 0; mi < 4; ++mi) {
        int row = wr * 64 + mi * 16 + ll;
        af[mi] = *(const short8*)&la[row * 64 + ((ks * 32 + g * 8) ^ (l7 * 8))];
      }
#pragma unroll
      for (int ni = 0; ni < 4; ++ni) {
        int row = wc * 64 + ni * 16 + ll;
        bfr[ni] = *(const short8*)&lb[row * 64 + ((ks * 32 + g * 8) ^ (l7 * 8))];
      }
#pragma unroll
      for (int mi = 0; mi < 4; ++mi)
#pragma unroll
        for (int ni = 0; ni < 4; ++ni)
          acc[mi][ni] = MFMA16(af[mi], bfr[ni], acc[mi][ni]);
    }
    cur ^= 1;
  }

  if (MODE == 0) {
    const float QS = 0.18033688011112042f;  // 1/8 * log2(e)
#pragma unroll
    for (int ni = 0; ni < 4; ++ni) {
      int np = nt * 128 + wc * 64 + ni * 16 + ll;
      int tsel = np >> 10, hh = (np >> 6) & 15, dd = np & 63;
      float bv = bias[np];
#pragma unroll
      for (int mi = 0; mi < 4; ++mi) {
        int n0r = mt * 128 + wr * 64 + mi * 16 + g * 4;
        floatx4 v = acc[mi][ni];
        if (tsel == 0) {
#pragma unroll
          for (int i = 0; i < 4; ++i)
            Qo[((size_t)hh * 4096 + n0r + i) * 64 + dd] = f2bf((v[i] + bv) * QS);
        } else if (tsel == 1) {
#pragma unroll
          for (int i = 0; i < 4; ++i)
            Ko[((size_t)hh * 4096 + n0r + i) * 64 + dd] = f2bf(v[i] + bv);
        } else {  // V transposed: Vt[h][d][n]
          uint2 pk; pk.x = pack2(v[0] + bv, v[1] + bv); pk.y = pack2(v[2] + bv, v[3] + bv);
          *(uint2*)&Vto[((size_t)hh * 64 + dd) * 4096 + n0r] = pk;
        }
      }
    }
  } else {
#pragma unroll
    for (int ni = 0; ni < 4; ++ni) {
      int col = nt * 128 + wc * 64 + ni * 16 + ll;
      float bv = bias[col];
#pragma unroll
      for (int mi = 0; mi < 4; ++mi) {
        int r0 = mt * 128 + wr * 64 + mi * 16 + g * 4;
#pragma unroll
        for (int i = 0; i < 4; ++i)
          outF[(size_t)(r0 + i) * 1024 + col] = acc[mi][ni][i] + bv;
      }
    }
  }
}

// ---------------- flash attention ----------------
// grid 512 flat, 4 waves/block, wave owns 32 q-rows (block = 128 q).
// XCD pinning: bid&7 = XCD; 2 heads/XCD -> K/V L2-resident (proven r3: FETCH
// dropped to ~compulsory).
// NEW (r4): K/V tiles (KVBLK=64) staged in LDS via global_load_lds, double-
// buffered, SHARED by all 4 waves (r3 had every wave streaming K/V from
// global -> 4x redundant VMEM traffic, latency-bound at all-pipes-idle).
// m97 pipeline: barrier at loop top drains prefetch; stage(t+1) issued right
// after, flies during compute of t. XOR-swizzle ((row&7)<<4) on K/V tiles
// (pre-swizzled global source, m173) -> conflict-free ds_read_b128.
// Swapped QK^T: S^T = mfma(K,Q), softmax in-register per q-row + shfl_xor.
// P roundtrips per-wave LDS (swizzled). LDS 48KB -> 3 blocks/CU.
__global__ __launch_bounds__(256, 3)
void attn_kernel(const u16* __restrict__ Qb, const u16* __restrict__ Kb,
                 const u16* __restrict__ Vt, u16* __restrict__ aout) {
  __shared__ __align__(16) u16 lK[2][64 * 64];   // [key][d]   8KB/buf
  __shared__ __align__(16) u16 lV[2][64 * 64];   // [d][key]   8KB/buf
  __shared__ __align__(16) u16 lP[4][32 * 64];   // per-wave [q][key] 4KB
  const int tid = threadIdx.x, l = tid & 63, w = tid >> 6;
  const int g = l >> 4, ll = l & 15;
  const int swz = (ll & 7) << 4;       // read-side XOR swizzle (bytes)
  const int bid = blockIdx.x;
  const int h = (bid & 7) * 2 + ((bid >> 3) & 1);
  const int qb = bid >> 4;             // 0..31
  const int q0 = qb * 128 + w * 32;
  const u16* Qh = Qb + (size_t)h * 4096 * 64;
  const char* Khc = (const char*)(Kb + (size_t)h * 4096 * 64);
  const char* Vhc = (const char*)(Vt + (size_t)h * 64 * 4096);
  char* myP = (char*)&lP[w][0];

  // per-lane pre-swizzled staging offsets (bytes); row_local = l>>3 so the
  // XOR term is lane-constant across all stage calls (w*16, j*8 are mult of 8)
  const int sswz = (((l & 7) * 16) ^ ((l >> 3) << 4));
  const int koff = (l >> 3) * 128 + sswz;
  const int voff = (l >> 3) * 8192 + sswz;

  short8 qf[2][2];
#pragma unroll
  for (int c = 0; c < 2; ++c)
#pragma unroll
    for (int ks = 0; ks < 2; ++ks)
      qf[c][ks] = *(const short8*)&Qh[(size_t)(q0 + c * 16 + ll) * 64 + ks * 32 + g * 8];

  auto stage = [&](int kt, int buf) {
    // K tile: rows kt*64..+64 of Kh (128B rows); wave w covers 16 rows
    const char* ks_ = Khc + (size_t)(kt * 64 + w * 16) * 128 + koff;
    char* kd = (char*)&lK[buf][0] + w * 2048;
    gl2lds16(ks_, kd);
    gl2lds16(ks_ + 8 * 128, kd + 1024);
    // V tile: cols kt*64..+64 of Vt (8192B rows); wave w covers d rows w*16..+16
    const char* vs = Vhc + (size_t)(w * 16) * 8192 + (size_t)kt * 128 + voff;
    char* vd = (char*)&lV[buf][0] + w * 2048;
    gl2lds16(vs, vd);
    gl2lds16(vs + 8 * 8192, vd + 1024);
  };

  float m[2] = {-1e30f, -1e30f}, lsum[2] = {0.f, 0.f};
  floatx4 o[4][2];
#pragma unroll
  for (int fd = 0; fd < 4; ++fd)
#pragma unroll
    for (int c = 0; c < 2; ++c) o[fd][c] = floatx4{0.f, 0.f, 0.f, 0.f};

  stage(0, 0);
  int cur = 0;
  for (int kt = 0; kt < 64; ++kt) {
    __syncthreads();                         // buf[cur] staged (vmcnt drained)
    if (kt + 1 < 64) stage(kt + 1, cur ^ 1); // prefetch next tile
    const char* Ktile = (const char*)&lK[cur][0];
    const char* Vtile = (const char*)&lV[cur][0];

    floatx4 s[2][4];
#pragma unroll
    for (int c = 0; c < 2; ++c)
#pragma unroll
      for (int fr = 0; fr < 4; ++fr) s[c][fr] = floatx4{0.f, 0.f, 0.f, 0.f};

#pragma unroll
    for (int ks = 0; ks < 2; ++ks) {
      short8 kf[4];
#pragma unroll
      for (int fr = 0; fr < 4; ++fr)
        kf[fr] = *(const short8*)(Ktile + (fr * 16 + ll) * 128 + ((ks * 64 + g * 16) ^ swz));
#pragma unroll
      for (int fr = 0; fr < 4; ++fr)
#pragma unroll
        for (int c = 0; c < 2; ++c)
          s[c][fr] = MFMA16(kf[fr], qf[c][ks], s[c][fr]);
    }

    // online softmax (base-2; scale folded into Q)
#pragma unroll
    for (int c = 0; c < 2; ++c) {
      float tm = -1e30f;
#pragma unroll
      for (int fr = 0; fr < 4; ++fr)
#pragma unroll
        for (int i = 0; i < 4; ++i) tm = fmaxf(tm, s[c][fr][i]);
      tm = fmaxf(tm, __shfl_xor(tm, 16));
      tm = fmaxf(tm, __shfl_xor(tm, 32));
      float mn = fmaxf(m[c], tm);
      float al = __builtin_amdgcn_exp2f(m[c] - mn);
      float rs = 0.f;
#pragma unroll
      for (int fr = 0; fr < 4; ++fr)
#pragma unroll
        for (int i = 0; i < 4; ++i) {
          float p = __builtin_amdgcn_exp2f(s[c][fr][i] - mn);
          s[c][fr][i] = p;
          rs += p;
        }
      rs += __shfl_xor(rs, 16);
      rs += __shfl_xor(rs, 32);
      lsum[c] = lsum[c] * al + rs;
      m[c] = mn;
#pragma unroll
      for (int fd = 0; fd < 4; ++fd) o[fd][c] *= al;
    }

    // P -> per-wave LDS [32 q][64 k] bf16 (128B rows), same XOR swizzle
#pragma unroll
    for (int c = 0; c < 2; ++c) {
      char* rowp = myP + (c * 16 + ll) * 128;
#pragma unroll
      for (int fr = 0; fr < 4; ++fr) {
        uint2 pk;
        pk.x = pack2(s[c][fr][0], s[c][fr][1]);
        pk.y = pack2(s[c][fr][2], s[c][fr][3]);
        *(uint2*)(rowp + ((fr * 32 + g * 8) ^ swz)) = pk;
      }
    }

    // PV: O^T += V^T x P^T
#pragma unroll
    for (int ks2 = 0; ks2 < 2; ++ks2) {
      short8 vf[4];
#pragma unroll
      for (int fd = 0; fd < 4; ++fd)
        vf[fd] = *(const short8*)(Vtile + (fd * 16 + ll) * 128 + ((ks2 * 64 + g * 16) ^ swz));
      short8 pf[2];
#pragma unroll
      for (int c = 0; c < 2; ++c)
        pf[c] = *(const short8*)(myP + (c * 16 + ll) * 128 + ((ks2 * 64 + g * 16) ^ swz));
#pragma unroll
      for (int fd = 0; fd < 4; ++fd)
#pragma unroll
        for (int c = 0; c < 2; ++c)
          o[fd][c] = MFMA16(vf[fd], pf[c], o[fd][c]);
    }
    cur ^= 1;
  }

  // normalize + write attn_out[n][h*64+d] bf16
#pragma unroll
  for (int c = 0; c < 2; ++c) {
    float inv = 1.f / lsum[c];
    int n = q0 + c * 16 + ll;
#pragma unroll
    for (int fd = 0; fd < 4; ++fd) {
      uint2 pk;
      pk.x = pack2(o[fd][c][0] * inv, o[fd][c][1] * inv);
      pk.y = pack2(o[fd][c][2] * inv, o[fd][c][3] * inv);
      *(uint2*)&aout[(size_t)n * 1024 + h * 64 + fd * 16 + g * 4] = pk;
    }
  }
}

extern "C" void kernel_launch(void* const* d_in, const int* in_sizes, int n_in,
                              void* d_out, int out_size, void* d_ws, size_t ws_size,
                              hipStream_t stream) {
  const float* x    = (const float*)d_in[0];
  const float* Wqkv = (const float*)d_in[1];
  const float* bqkv = (const float*)d_in[2];
  const float* Wout = (const float*)d_in[3];
  const float* bout = (const float*)d_in[4];
  float* out = (float*)d_out;

  // d_ws usage: 24 MB total (defensive — ws_size is harness-chosen).
  u16* ws    = (u16*)d_ws;
  u16* xb    = ws;                            // 4M u16 = 8 MB (reused as aout)
  u16* wqkvT = xb + (size_t)4096 * 1024;      // 6 MB
  u16* woutT = wqkvT + (size_t)3072 * 1024;   // 2 MB
  u16* Vt    = woutT + (size_t)1024 * 1024;   // 8 MB
  u16* aout  = xb;                            // alias: xb dead after gemm<0>

  // Q and K live in d_out (16 MB fp32 buffer; holds exactly 2 x 8 MB bf16).
  // Both are dead before gemm<1> rewrites d_out in full.
  u16* Qb = (u16*)d_out;                      // 8 MB
  u16* Kb = Qb + (size_t)16 * 4096 * 64;      // 8 MB

  cvt_x<<<2048, 256, 0, stream>>>(x, xb);
  tr_cvt<<<dim3(48, 16), 256, 0, stream>>>(Wqkv, wqkvT, 1024, 3072);
  tr_cvt<<<dim3(16, 16), 256, 0, stream>>>(Wout, woutT, 1024, 1024);
  gemm_bt<0><<<dim3(32, 24), 256, 0, stream>>>(xb, wqkvT, 1024, bqkv, nullptr, Qb, Kb, Vt);
  attn_kernel<<<512, 256, 0, stream>>>(Qb, Kb, Vt, aout);
  gemm_bt<1><<<dim3(32, 8), 256, 0, stream>>>(aout, woutT, 1024, bout, out,
                                              nullptr, nullptr, nullptr);
}

// Round 5
// 256.951 us; speedup vs baseline: 2.2520x; 1.0033x over previous
//
#include <hip/hip_runtime.h>
#include <stdint.h>

using short8  = __attribute__((ext_vector_type(8))) short;   // 8 x bf16 (4 VGPRs)
using floatx4 = __attribute__((ext_vector_type(4))) float;   // MFMA acc
using u16 = unsigned short;
using u32 = unsigned int;

#define MFMA16(A,B,C) __builtin_amdgcn_mfma_f32_16x16x32_bf16((A),(B),(C),0,0,0)

static __device__ __forceinline__ u16 f2bf(float f) {
  u32 u = __float_as_uint(f);
  u += 0x7fffu + ((u >> 16) & 1u);   // RNE
  return (u16)(u >> 16);
}
static __device__ __forceinline__ u32 pack2(float a, float b) {
  return (u32)f2bf(a) | ((u32)f2bf(b) << 16);
}

// CK-style global->LDS direct copy, 16B per lane. LDS dest must be wave-uniform
// base (HW adds lane*16); global src is per-lane (carries the swizzle).
static __device__ __forceinline__ void gl2lds16(const void* g, void* l) {
  auto gp = reinterpret_cast<__attribute__((address_space(1))) u32*>(
      reinterpret_cast<uintptr_t>(g));
  auto lp = reinterpret_cast<__attribute__((address_space(3))) u32*>(
      reinterpret_cast<uintptr_t>(l));
  __builtin_amdgcn_global_load_lds(gp, lp, 16, 0, 0);
}

// ---------------- prep: fp32 -> bf16 convert ----------------
__global__ __launch_bounds__(256) void cvt_x(const float* __restrict__ x,
                                             u16* __restrict__ xb) {
  size_t i = ((size_t)blockIdx.x * 256 + threadIdx.x) * 8;
  float4 a = *(const float4*)&x[i];
  float4 b = *(const float4*)&x[i + 4];
  uint4 pk = make_uint4(pack2(a.x, a.y), pack2(a.z, a.w),
                        pack2(b.x, b.y), pack2(b.z, b.w));
  *(uint4*)&xb[i] = pk;
}

// W[K][N] fp32 -> Wt[N][K] bf16 (tiled 64x64 transpose through LDS)
__global__ __launch_bounds__(256) void tr_cvt(const float* __restrict__ W,
                                              u16* __restrict__ Wt,
                                              int K, int N) {
  __shared__ u16 t[64][72];   // +8 pad
  const int tid = threadIdx.x;
  const int n0 = blockIdx.x * 64, k0 = blockIdx.y * 64;
#pragma unroll
  for (int i = 0; i < 4; ++i) {
    int c = i * 256 + tid;
    int r = c >> 4, co = (c & 15) * 4;
    float4 v = *(const float4*)&W[(size_t)(k0 + r) * N + n0 + co];
    uint2 pk; pk.x = pack2(v.x, v.y); pk.y = pack2(v.z, v.w);
    *(uint2*)&t[r][co] = pk;
  }
  __syncthreads();
#pragma unroll
  for (int i = 0; i < 2; ++i) {
    int c = i * 256 + tid;
    int n = c >> 3, ko = (c & 7) * 8;
    u16 o[8];
#pragma unroll
    for (int j = 0; j < 8; ++j) o[j] = t[ko + j][n];
    uint4 pk = make_uint4((u32)o[0] | ((u32)o[1] << 16), (u32)o[2] | ((u32)o[3] << 16),
                          (u32)o[4] | ((u32)o[5] << 16), (u32)o[6] | ((u32)o[7] << 16));
    *(uint4*)&Wt[(size_t)(n0 + n) * K + k0 + ko] = pk;
  }
}

// ---------------- GEMM: A[M][K] bf16 x Bt[N][K] bf16 ----------------
// 128x128 tile, BK=64, 4 waves (2x2), each 64x64. Double-buffered LDS via
// global_load_lds(16B) with pre-swizzled global source (XOR chunk swizzle).
// MODE 0: epilogue routes QKV (Q scaled by SCALE*log2e, V transposed AND
//         key-permuted so attn's PV B-operand is lane-local — see attn).
// MODE 1: fp32 + bias -> d_out.
template <int MODE>
__global__ __launch_bounds__(256)
void gemm_bt(const u16* __restrict__ A, const u16* __restrict__ Bt, int Kd,
             const float* __restrict__ bias, float* __restrict__ outF,
             u16* __restrict__ Qo, u16* __restrict__ Ko, u16* __restrict__ Vto) {
  __shared__ __align__(16) u16 lA[2][128 * 64];
  __shared__ __align__(16) u16 lB[2][128 * 64];
  const int tid = threadIdx.x;
  const int l = tid & 63, w = tid >> 6;
  const int g = l >> 4, ll = l & 15, l7 = l & 7, rl = l >> 3;
  const int mt = blockIdx.x, nt = blockIdx.y;
  const int wr = w >> 1, wc = w & 1;
  const int swz = ((l7 ^ rl) << 4);  // inverse-swizzle on the global source

  const char* srcA = (const char*)(A + (size_t)(mt * 128 + w * 32 + rl) * Kd) + swz;
  const char* srcB = (const char*)(Bt + (size_t)(nt * 128 + w * 32 + rl) * Kd) + swz;
  const size_t rstep = (size_t)8 * Kd * 2;

  floatx4 acc[4][4];
#pragma unroll
  for (int i = 0; i < 4; ++i)
#pragma unroll
    for (int j = 0; j < 4; ++j) acc[i][j] = floatx4{0.f, 0.f, 0.f, 0.f};

  const int NT = Kd >> 6;
  auto stage = [&](int t, int buf) {
    const char* a = srcA + (size_t)t * 128;
    const char* b = srcB + (size_t)t * 128;
    char* la = (char*)&lA[buf][0] + w * 4096;
    char* lb = (char*)&lB[buf][0] + w * 4096;
#pragma unroll
    for (int j = 0; j < 4; ++j) {
      gl2lds16(a + j * rstep, la + j * 1024);
      gl2lds16(b + j * rstep, lb + j * 1024);
    }
  };

  stage(0, 0);
  int cur = 0;
  for (int t = 0; t < NT; ++t) {
    __syncthreads();                       // drains vmcnt then barrier
    if (t + 1 < NT) stage(t + 1, cur ^ 1); // prefetch overlaps compute
    const u16* la = &lA[cur][0];
    const u16* lb = &lB[cur][0];
#pragma unroll
    for (int ks = 0; ks < 2; ++ks) {
      short8 af[4], bfr[4];
#pragma unroll
      for (int mi = 0; mi < 4; ++mi) {
        int row = wr * 64 + mi * 16 + ll;
        af[mi] = *(const short8*)&la[row * 64 + ((ks * 32 + g * 8) ^ (l7 * 8))];
      }
#pragma unroll
      for (int ni = 0; ni < 4; ++ni) {
        int row = wc * 64 + ni * 16 + ll;
        bfr[ni] = *(const short8*)&lb[row * 64 + ((ks * 32 + g * 8) ^ (l7 * 8))];
      }
#pragma unroll
      for (int mi = 0; mi < 4; ++mi)
#pragma unroll
        for (int ni = 0; ni < 4; ++ni)
          acc[mi][ni] = MFMA16(af[mi], bfr[ni], acc[mi][ni]);
    }
    cur ^= 1;
  }

  if (MODE == 0) {
    const float QS = 0.18033688011112042f;  // 1/8 * log2(e)
#pragma unroll
    for (int ni = 0; ni < 4; ++ni) {
      int np = nt * 128 + wc * 64 + ni * 16 + ll;
      int tsel = np >> 10, hh = (np >> 6) & 15, dd = np & 63;
      float bv = bias[np];
#pragma unroll
      for (int mi = 0; mi < 4; ++mi) {
        int n0r = mt * 128 + wr * 64 + mi * 16 + g * 4;
        floatx4 v = acc[mi][ni];
        if (tsel == 0) {
#pragma unroll
          for (int i = 0; i < 4; ++i)
            Qo[((size_t)hh * 4096 + n0r + i) * 64 + dd] = f2bf((v[i] + bv) * QS);
        } else if (tsel == 1) {
#pragma unroll
          for (int i = 0; i < 4; ++i)
            Ko[((size_t)hh * 4096 + n0r + i) * 64 + dd] = f2bf(v[i] + bv);
        } else {
          // V transposed: Vt[h][d][perm(n)]. Key-permutation within each
          // 64-key group: bits [f1 f0 g1 g0 i1 i0] -> [f1 g1 g0 f0 i1 i0]
          // so attn's PV B-fragment (k-slot g*8+j) is lane-local after QK^T.
          int k6 = n0r & 63;
          int p6 = (k6 & 0x23) | ((k6 & 0x0C) << 1) | ((k6 & 0x10) >> 2);
          int vcol = (n0r & ~63) | p6;
          uint2 pk; pk.x = pack2(v[0] + bv, v[1] + bv); pk.y = pack2(v[2] + bv, v[3] + bv);
          *(uint2*)&Vto[((size_t)hh * 64 + dd) * 4096 + vcol] = pk;
        }
      }
    }
  } else {
#pragma unroll
    for (int ni = 0; ni < 4; ++ni) {
      int col = nt * 128 + wc * 64 + ni * 16 + ll;
      float bv = bias[col];
#pragma unroll
      for (int mi = 0; mi < 4; ++mi) {
        int r0 = mt * 128 + wr * 64 + mi * 16 + g * 4;
#pragma unroll
        for (int i = 0; i < 4; ++i)
          outF[(size_t)(r0 + i) * 1024 + col] = acc[mi][ni][i] + bv;
      }
    }
  }
}

// ---------------- flash attention ----------------
// grid 512 flat, 4 waves/block, wave owns 32 q-rows (block = 128 q).
// XCD pinning (proven r3/r4: FETCH ~= compulsory): bid&7 = XCD, 2 heads/XCD.
// K/V staged in LDS (KVBLK=64, double-buffered global_load_lds, m97 pipeline,
// XOR-swizzled -> conflict-free ds_read_b128).
// NEW (r5): NO P-LDS roundtrip. Swapped QK^T leaves lane (g,ll) holding P for
// keys fr*16+g*4+i; V's global key order is bit-shuffle-permuted (gemm<0>
// epilogue) so PV's B-operand k-slot g*8+j maps exactly to those registers.
// P path = pack2 only. Softmax is key-permutation-invariant.
// NEW (r5): defer-rescale (T13, THR=8 in exp2 domain) + s_setprio around MFMA.
__global__ __launch_bounds__(256)
void attn_kernel(const u16* __restrict__ Qb, const u16* __restrict__ Kb,
                 const u16* __restrict__ Vt, u16* __restrict__ aout) {
  __shared__ __align__(16) u16 lK[2][64 * 64];   // [key][d]   8KB/buf
  __shared__ __align__(16) u16 lV[2][64 * 64];   // [d][key']  8KB/buf
  const int tid = threadIdx.x, l = tid & 63, w = tid >> 6;
  const int g = l >> 4, ll = l & 15;
  const int swz = (ll & 7) << 4;       // read-side XOR swizzle (bytes)
  const int bid = blockIdx.x;
  const int h = (bid & 7) * 2 + ((bid >> 3) & 1);
  const int qb = bid >> 4;             // 0..31
  const int q0 = qb * 128 + w * 32;
  const u16* Qh = Qb + (size_t)h * 4096 * 64;
  const char* Khc = (const char*)(Kb + (size_t)h * 4096 * 64);
  const char* Vhc = (const char*)(Vt + (size_t)h * 64 * 4096);

  // per-lane pre-swizzled staging offsets (bytes)
  const int sswz = (((l & 7) * 16) ^ ((l >> 3) << 4));
  const int koff = (l >> 3) * 128 + sswz;
  const int voff = (l >> 3) * 8192 + sswz;

  short8 qf[2][2];
#pragma unroll
  for (int c = 0; c < 2; ++c)
#pragma unroll
    for (int ks = 0; ks < 2; ++ks)
      qf[c][ks] = *(const short8*)&Qh[(size_t)(q0 + c * 16 + ll) * 64 + ks * 32 + g * 8];

  auto stage = [&](int kt, int buf) {
    const char* ks_ = Khc + (size_t)(kt * 64 + w * 16) * 128 + koff;
    char* kd = (char*)&lK[buf][0] + w * 2048;
    gl2lds16(ks_, kd);
    gl2lds16(ks_ + 8 * 128, kd + 1024);
    const char* vs = Vhc + (size_t)(w * 16) * 8192 + (size_t)kt * 128 + voff;
    char* vd = (char*)&lV[buf][0] + w * 2048;
    gl2lds16(vs, vd);
    gl2lds16(vs + 8 * 8192, vd + 1024);
  };

  float m[2] = {-1e30f, -1e30f}, lsum[2] = {0.f, 0.f};
  floatx4 o[4][2];
#pragma unroll
  for (int fd = 0; fd < 4; ++fd)
#pragma unroll
    for (int c = 0; c < 2; ++c) o[fd][c] = floatx4{0.f, 0.f, 0.f, 0.f};

  stage(0, 0);
  int cur = 0;
  for (int kt = 0; kt < 64; ++kt) {
    __syncthreads();                         // buf[cur] staged (vmcnt drained)
    if (kt + 1 < 64) stage(kt + 1, cur ^ 1); // prefetch next tile
    const char* Ktile = (const char*)&lK[cur][0];
    const char* Vtile = (const char*)&lV[cur][0];

    floatx4 s[2][4];
#pragma unroll
    for (int c = 0; c < 2; ++c)
#pragma unroll
      for (int fr = 0; fr < 4; ++fr) s[c][fr] = floatx4{0.f, 0.f, 0.f, 0.f};

    __builtin_amdgcn_s_setprio(1);
#pragma unroll
    for (int ks = 0; ks < 2; ++ks) {
      short8 kf[4];
#pragma unroll
      for (int fr = 0; fr < 4; ++fr)
        kf[fr] = *(const short8*)(Ktile + (fr * 16 + ll) * 128 + ((ks * 64 + g * 16) ^ swz));
#pragma unroll
      for (int fr = 0; fr < 4; ++fr)
#pragma unroll
        for (int c = 0; c < 2; ++c)
          s[c][fr] = MFMA16(kf[fr], qf[c][ks], s[c][fr]);
    }
    __builtin_amdgcn_s_setprio(0);

    // online softmax (base-2; scale folded into Q); defer-rescale THR=8
#pragma unroll
    for (int c = 0; c < 2; ++c) {
      float tm = -1e30f;
#pragma unroll
      for (int fr = 0; fr < 4; ++fr)
#pragma unroll
        for (int i = 0; i < 4; ++i) tm = fmaxf(tm, s[c][fr][i]);
      tm = fmaxf(tm, __shfl_xor(tm, 16));
      tm = fmaxf(tm, __shfl_xor(tm, 32));
      if (!__all(tm <= m[c] + 8.0f)) {      // wave-uniform branch
        float mn = fmaxf(m[c], tm);
        float al = __builtin_amdgcn_exp2f(m[c] - mn);
        lsum[c] *= al;
#pragma unroll
        for (int fd = 0; fd < 4; ++fd) o[fd][c] *= al;
        m[c] = mn;
      }
      float rs = 0.f;
#pragma unroll
      for (int fr = 0; fr < 4; ++fr)
#pragma unroll
        for (int i = 0; i < 4; ++i) {
          float p = __builtin_amdgcn_exp2f(s[c][fr][i] - m[c]);
          s[c][fr][i] = p;
          rs += p;
        }
      rs += __shfl_xor(rs, 16);
      rs += __shfl_xor(rs, 32);
      lsum[c] += rs;
    }

    // pack P -> in-register PV B-fragments (V key-permuted to match)
    short8 pf[2][2];
#pragma unroll
    for (int c = 0; c < 2; ++c) {
      union { short8 v; u32 u[4]; } pu0, pu1;
      pu0.u[0] = pack2(s[c][0][0], s[c][0][1]);
      pu0.u[1] = pack2(s[c][0][2], s[c][0][3]);
      pu0.u[2] = pack2(s[c][1][0], s[c][1][1]);
      pu0.u[3] = pack2(s[c][1][2], s[c][1][3]);
      pu1.u[0] = pack2(s[c][2][0], s[c][2][1]);
      pu1.u[1] = pack2(s[c][2][2], s[c][2][3]);
      pu1.u[2] = pack2(s[c][3][0], s[c][3][1]);
      pu1.u[3] = pack2(s[c][3][2], s[c][3][3]);
      pf[c][0] = pu0.v;
      pf[c][1] = pu1.v;
    }

    // PV: O^T += V^T x P^T
    __builtin_amdgcn_s_setprio(1);
#pragma unroll
    for (int ks2 = 0; ks2 < 2; ++ks2) {
      short8 vf[4];
#pragma unroll
      for (int fd = 0; fd < 4; ++fd)
        vf[fd] = *(const short8*)(Vtile + (fd * 16 + ll) * 128 + ((ks2 * 64 + g * 16) ^ swz));
#pragma unroll
      for (int fd = 0; fd < 4; ++fd)
#pragma unroll
        for (int c = 0; c < 2; ++c)
          o[fd][c] = MFMA16(vf[fd], pf[c][ks2], o[fd][c]);
    }
    __builtin_amdgcn_s_setprio(0);
    cur ^= 1;
  }

  // normalize + write attn_out[n][h*64+d] bf16
#pragma unroll
  for (int c = 0; c < 2; ++c) {
    float inv = 1.f / lsum[c];
    int n = q0 + c * 16 + ll;
#pragma unroll
    for (int fd = 0; fd < 4; ++fd) {
      uint2 pk;
      pk.x = pack2(o[fd][c][0] * inv, o[fd][c][1] * inv);
      pk.y = pack2(o[fd][c][2] * inv, o[fd][c][3] * inv);
      *(uint2*)&aout[(size_t)n * 1024 + h * 64 + fd * 16 + g * 4] = pk;
    }
  }
}

extern "C" void kernel_launch(void* const* d_in, const int* in_sizes, int n_in,
                              void* d_out, int out_size, void* d_ws, size_t ws_size,
                              hipStream_t stream) {
  const float* x    = (const float*)d_in[0];
  const float* Wqkv = (const float*)d_in[1];
  const float* bqkv = (const float*)d_in[2];
  const float* Wout = (const float*)d_in[3];
  const float* bout = (const float*)d_in[4];
  float* out = (float*)d_out;

  // d_ws usage: 24 MB total (defensive — ws_size is harness-chosen).
  u16* ws    = (u16*)d_ws;
  u16* xb    = ws;                            // 4M u16 = 8 MB (reused as aout)
  u16* wqkvT = xb + (size_t)4096 * 1024;      // 6 MB
  u16* woutT = wqkvT + (size_t)3072 * 1024;   // 2 MB
  u16* Vt    = woutT + (size_t)1024 * 1024;   // 8 MB
  u16* aout  = xb;                            // alias: xb dead after gemm<0>

  // Q and K live in d_out (16 MB fp32 buffer; holds exactly 2 x 8 MB bf16).
  // Both are dead before gemm<1> rewrites d_out in full.
  u16* Qb = (u16*)d_out;                      // 8 MB
  u16* Kb = Qb + (size_t)16 * 4096 * 64;      // 8 MB

  cvt_x<<<2048, 256, 0, stream>>>(x, xb);
  tr_cvt<<<dim3(48, 16), 256, 0, stream>>>(Wqkv, wqkvT, 1024, 3072);
  tr_cvt<<<dim3(16, 16), 256, 0, stream>>>(Wout, woutT, 1024, 1024);
  gemm_bt<0><<<dim3(32, 24), 256, 0, stream>>>(xb, wqkvT, 1024, bqkv, nullptr, Qb, Kb, Vt);
  attn_kernel<<<512, 256, 0, stream>>>(Qb, Kb, Vt, aout);
  gemm_bt<1><<<dim3(32, 8), 256, 0, stream>>>(aout, woutT, 1024, bout, out,
                                              nullptr, nullptr, nullptr);
}

// Round 6
// 243.373 us; speedup vs baseline: 2.3776x; 1.0558x over previous
//
#include <hip/hip_runtime.h>
#include <stdint.h>

using short8  = __attribute__((ext_vector_type(8))) short;   // 8 x bf16 (4 VGPRs)
using floatx4 = __attribute__((ext_vector_type(4))) float;   // MFMA acc
using u16 = unsigned short;
using u32 = unsigned int;

#define MFMA16(A,B,C) __builtin_amdgcn_mfma_f32_16x16x32_bf16((A),(B),(C),0,0,0)

// Native packed f32->bf16 (RNE), 1 instr for 2 values: lo=a, hi=b.
static __device__ __forceinline__ u32 cvtpk(float a, float b) {
  u32 r;
  asm("v_cvt_pk_bf16_f32 %0, %1, %2" : "=v"(r) : "v"(a), "v"(b));
  return r;
}

// CK-style global->LDS direct copy, 16B per lane. LDS dest must be wave-uniform
// base (HW adds lane*16); global src is per-lane (carries the swizzle).
static __device__ __forceinline__ void gl2lds16(const void* g, void* l) {
  auto gp = reinterpret_cast<__attribute__((address_space(1))) u32*>(
      reinterpret_cast<uintptr_t>(g));
  auto lp = reinterpret_cast<__attribute__((address_space(3))) u32*>(
      reinterpret_cast<uintptr_t>(l));
  __builtin_amdgcn_global_load_lds(gp, lp, 16, 0, 0);
}

// ---------------- prep: fp32 -> bf16 convert ----------------
__global__ __launch_bounds__(256) void cvt_x(const float* __restrict__ x,
                                             u16* __restrict__ xb) {
  size_t i = ((size_t)blockIdx.x * 256 + threadIdx.x) * 8;
  float4 a = *(const float4*)&x[i];
  float4 b = *(const float4*)&x[i + 4];
  uint4 pk = make_uint4(cvtpk(a.x, a.y), cvtpk(a.z, a.w),
                        cvtpk(b.x, b.y), cvtpk(b.z, b.w));
  *(uint4*)&xb[i] = pk;
}

// W[K][N] fp32 -> Wt[N][K] bf16 (tiled 64x64 transpose through LDS)
__global__ __launch_bounds__(256) void tr_cvt(const float* __restrict__ W,
                                              u16* __restrict__ Wt,
                                              int K, int N) {
  __shared__ u16 t[64][72];   // +8 pad
  const int tid = threadIdx.x;
  const int n0 = blockIdx.x * 64, k0 = blockIdx.y * 64;
#pragma unroll
  for (int i = 0; i < 4; ++i) {
    int c = i * 256 + tid;
    int r = c >> 4, co = (c & 15) * 4;
    float4 v = *(const float4*)&W[(size_t)(k0 + r) * N + n0 + co];
    uint2 pk; pk.x = cvtpk(v.x, v.y); pk.y = cvtpk(v.z, v.w);
    *(uint2*)&t[r][co] = pk;
  }
  __syncthreads();
#pragma unroll
  for (int i = 0; i < 2; ++i) {
    int c = i * 256 + tid;
    int n = c >> 3, ko = (c & 7) * 8;
    u16 o[8];
#pragma unroll
    for (int j = 0; j < 8; ++j) o[j] = t[ko + j][n];
    uint4 pk = make_uint4((u32)o[0] | ((u32)o[1] << 16), (u32)o[2] | ((u32)o[3] << 16),
                          (u32)o[4] | ((u32)o[5] << 16), (u32)o[6] | ((u32)o[7] << 16));
    *(uint4*)&Wt[(size_t)(n0 + n) * K + k0 + ko] = pk;
  }
}

// ---------------- GEMM: A[M][K] bf16 x Bt[N][K] bf16 ----------------
// 128x128 tile, BK=64, 4 waves (2x2), each 64x64. Double-buffered LDS via
// global_load_lds(16B) with pre-swizzled global source (XOR chunk swizzle).
// MODE 0: epilogue routes QKV (Q scaled by SCALE*log2e, V transposed AND
//         key-permuted so attn's PV B-operand is lane-local — see attn).
// MODE 1: fp32 + bias -> d_out.
template <int MODE>
__global__ __launch_bounds__(256)
void gemm_bt(const u16* __restrict__ A, const u16* __restrict__ Bt, int Kd,
             const float* __restrict__ bias, float* __restrict__ outF,
             u16* __restrict__ Qo, u16* __restrict__ Ko, u16* __restrict__ Vto) {
  __shared__ __align__(16) u16 lA[2][128 * 64];
  __shared__ __align__(16) u16 lB[2][128 * 64];
  const int tid = threadIdx.x;
  const int l = tid & 63, w = tid >> 6;
  const int g = l >> 4, ll = l & 15, l7 = l & 7, rl = l >> 3;
  const int mt = blockIdx.x, nt = blockIdx.y;
  const int wr = w >> 1, wc = w & 1;
  const int swz = ((l7 ^ rl) << 4);  // inverse-swizzle on the global source

  const char* srcA = (const char*)(A + (size_t)(mt * 128 + w * 32 + rl) * Kd) + swz;
  const char* srcB = (const char*)(Bt + (size_t)(nt * 128 + w * 32 + rl) * Kd) + swz;
  const size_t rstep = (size_t)8 * Kd * 2;

  floatx4 acc[4][4];
#pragma unroll
  for (int i = 0; i < 4; ++i)
#pragma unroll
    for (int j = 0; j < 4; ++j) acc[i][j] = floatx4{0.f, 0.f, 0.f, 0.f};

  const int NT = Kd >> 6;
  auto stage = [&](int t, int buf) {
    const char* a = srcA + (size_t)t * 128;
    const char* b = srcB + (size_t)t * 128;
    char* la = (char*)&lA[buf][0] + w * 4096;
    char* lb = (char*)&lB[buf][0] + w * 4096;
#pragma unroll
    for (int j = 0; j < 4; ++j) {
      gl2lds16(a + j * rstep, la + j * 1024);
      gl2lds16(b + j * rstep, lb + j * 1024);
    }
  };

  stage(0, 0);
  int cur = 0;
  for (int t = 0; t < NT; ++t) {
    __syncthreads();                       // drains vmcnt then barrier
    if (t + 1 < NT) stage(t + 1, cur ^ 1); // prefetch overlaps compute
    const u16* la = &lA[cur][0];
    const u16* lb = &lB[cur][0];
#pragma unroll
    for (int ks = 0; ks < 2; ++ks) {
      short8 af[4], bfr[4];
#pragma unroll
      for (int mi = 0; mi < 4; ++mi) {
        int row = wr * 64 + mi * 16 + ll;
        af[mi] = *(const short8*)&la[row * 64 + ((ks * 32 + g * 8) ^ (l7 * 8))];
      }
#pragma unroll
      for (int ni = 0; ni < 4; ++ni) {
        int row = wc * 64 + ni * 16 + ll;
        bfr[ni] = *(const short8*)&lb[row * 64 + ((ks * 32 + g * 8) ^ (l7 * 8))];
      }
#pragma unroll
      for (int mi = 0; mi < 4; ++mi)
#pragma unroll
        for (int ni = 0; ni < 4; ++ni)
          acc[mi][ni] = MFMA16(af[mi], bfr[ni], acc[mi][ni]);
    }
    cur ^= 1;
  }

  if (MODE == 0) {
    const float QS = 0.18033688011112042f;  // 1/8 * log2(e)
#pragma unroll
    for (int ni = 0; ni < 4; ++ni) {
      int np = nt * 128 + wc * 64 + ni * 16 + ll;
      int tsel = np >> 10, hh = (np >> 6) & 15, dd = np & 63;
      float bv = bias[np];
#pragma unroll
      for (int mi = 0; mi < 4; ++mi) {
        int n0r = mt * 128 + wr * 64 + mi * 16 + g * 4;
        floatx4 v = acc[mi][ni];
        if (tsel == 0) {
          u32 pa = cvtpk((v[0] + bv) * QS, (v[1] + bv) * QS);
          u32 pb = cvtpk((v[2] + bv) * QS, (v[3] + bv) * QS);
          size_t base = (size_t)hh * 4096 + n0r;
          Qo[(base + 0) * 64 + dd] = (u16)pa;
          Qo[(base + 1) * 64 + dd] = (u16)(pa >> 16);
          Qo[(base + 2) * 64 + dd] = (u16)pb;
          Qo[(base + 3) * 64 + dd] = (u16)(pb >> 16);
        } else if (tsel == 1) {
          u32 pa = cvtpk(v[0] + bv, v[1] + bv);
          u32 pb = cvtpk(v[2] + bv, v[3] + bv);
          size_t base = (size_t)hh * 4096 + n0r;
          Ko[(base + 0) * 64 + dd] = (u16)pa;
          Ko[(base + 1) * 64 + dd] = (u16)(pa >> 16);
          Ko[(base + 2) * 64 + dd] = (u16)pb;
          Ko[(base + 3) * 64 + dd] = (u16)(pb >> 16);
        } else {
          // V transposed: Vt[h][d][perm(n)]. Key-permutation within each
          // 64-key group: bits [f1 f0 g1 g0 i1 i0] -> [f1 g1 g0 f0 i1 i0]
          // so attn's PV B-fragment (k-slot g*8+j) is lane-local after QK^T.
          int k6 = n0r & 63;
          int p6 = (k6 & 0x23) | ((k6 & 0x0C) << 1) | ((k6 & 0x10) >> 2);
          int vcol = (n0r & ~63) | p6;
          uint2 pk; pk.x = cvtpk(v[0] + bv, v[1] + bv); pk.y = cvtpk(v[2] + bv, v[3] + bv);
          *(uint2*)&Vto[((size_t)hh * 64 + dd) * 4096 + vcol] = pk;
        }
      }
    }
  } else {
#pragma unroll
    for (int ni = 0; ni < 4; ++ni) {
      int col = nt * 128 + wc * 64 + ni * 16 + ll;
      float bv = bias[col];
#pragma unroll
      for (int mi = 0; mi < 4; ++mi) {
        int r0 = mt * 128 + wr * 64 + mi * 16 + g * 4;
#pragma unroll
        for (int i = 0; i < 4; ++i)
          outF[(size_t)(r0 + i) * 1024 + col] = acc[mi][ni][i] + bv;
      }
    }
  }
}

// ---------------- flash attention ----------------
// grid 512 flat, 4 waves/block, wave owns 32 q-rows (block = 128 q).
// XCD pinning (proven r3/r4: FETCH ~= compulsory): bid&7 = XCD, 2 heads/XCD.
// K/V staged in LDS (KVBLK=64, double-buffered global_load_lds, m97 pipeline,
// XOR-swizzled -> conflict-free ds_read_b128; 0 bank conflicts measured r5).
// No P-LDS roundtrip: V key-permuted in gemm<0> so PV B-operand is lane-local.
// r6: v_cvt_pk_bf16_f32 for all f32->bf16 packs (was ~10 VALU/pair manual RNE,
// the largest VALU block at 62% VALUBusy); lsum cross-lane reduce deferred to
// the end (per-lane partials; rescale factor al is row-uniform so consistent).
__global__ __launch_bounds__(256)
void attn_kernel(const u16* __restrict__ Qb, const u16* __restrict__ Kb,
                 const u16* __restrict__ Vt, u16* __restrict__ aout) {
  __shared__ __align__(16) u16 lK[2][64 * 64];   // [key][d]   8KB/buf
  __shared__ __align__(16) u16 lV[2][64 * 64];   // [d][key']  8KB/buf
  const int tid = threadIdx.x, l = tid & 63, w = tid >> 6;
  const int g = l >> 4, ll = l & 15;
  const int swz = (ll & 7) << 4;       // read-side XOR swizzle (bytes)
  const int bid = blockIdx.x;
  const int h = (bid & 7) * 2 + ((bid >> 3) & 1);
  const int qb = bid >> 4;             // 0..31
  const int q0 = qb * 128 + w * 32;
  const u16* Qh = Qb + (size_t)h * 4096 * 64;
  const char* Khc = (const char*)(Kb + (size_t)h * 4096 * 64);
  const char* Vhc = (const char*)(Vt + (size_t)h * 64 * 4096);

  // per-lane pre-swizzled staging offsets (bytes)
  const int sswz = (((l & 7) * 16) ^ ((l >> 3) << 4));
  const int koff = (l >> 3) * 128 + sswz;
  const int voff = (l >> 3) * 8192 + sswz;

  short8 qf[2][2];
#pragma unroll
  for (int c = 0; c < 2; ++c)
#pragma unroll
    for (int ks = 0; ks < 2; ++ks)
      qf[c][ks] = *(const short8*)&Qh[(size_t)(q0 + c * 16 + ll) * 64 + ks * 32 + g * 8];

  auto stage = [&](int kt, int buf) {
    const char* ks_ = Khc + (size_t)(kt * 64 + w * 16) * 128 + koff;
    char* kd = (char*)&lK[buf][0] + w * 2048;
    gl2lds16(ks_, kd);
    gl2lds16(ks_ + 8 * 128, kd + 1024);
    const char* vs = Vhc + (size_t)(w * 16) * 8192 + (size_t)kt * 128 + voff;
    char* vd = (char*)&lV[buf][0] + w * 2048;
    gl2lds16(vs, vd);
    gl2lds16(vs + 8 * 8192, vd + 1024);
  };

  float m[2] = {-1e30f, -1e30f}, lsum[2] = {0.f, 0.f};
  floatx4 o[4][2];
#pragma unroll
  for (int fd = 0; fd < 4; ++fd)
#pragma unroll
    for (int c = 0; c < 2; ++c) o[fd][c] = floatx4{0.f, 0.f, 0.f, 0.f};

  stage(0, 0);
  int cur = 0;
  for (int kt = 0; kt < 64; ++kt) {
    __syncthreads();                         // buf[cur] staged (vmcnt drained)
    if (kt + 1 < 64) stage(kt + 1, cur ^ 1); // prefetch next tile
    const char* Ktile = (const char*)&lK[cur][0];
    const char* Vtile = (const char*)&lV[cur][0];

    floatx4 s[2][4];
#pragma unroll
    for (int c = 0; c < 2; ++c)
#pragma unroll
      for (int fr = 0; fr < 4; ++fr) s[c][fr] = floatx4{0.f, 0.f, 0.f, 0.f};

    __builtin_amdgcn_s_setprio(1);
#pragma unroll
    for (int ks = 0; ks < 2; ++ks) {
      short8 kf[4];
#pragma unroll
      for (int fr = 0; fr < 4; ++fr)
        kf[fr] = *(const short8*)(Ktile + (fr * 16 + ll) * 128 + ((ks * 64 + g * 16) ^ swz));
#pragma unroll
      for (int fr = 0; fr < 4; ++fr)
#pragma unroll
        for (int c = 0; c < 2; ++c)
          s[c][fr] = MFMA16(kf[fr], qf[c][ks], s[c][fr]);
    }
    __builtin_amdgcn_s_setprio(0);

    // online softmax (base-2; scale folded into Q); defer-rescale THR=8;
    // lsum kept as PER-LANE partial (cross-lane reduce deferred to the end).
#pragma unroll
    for (int c = 0; c < 2; ++c) {
      float t0 = fmaxf(fmaxf(s[c][0][0], s[c][0][1]), fmaxf(s[c][0][2], s[c][0][3]));
      float t1 = fmaxf(fmaxf(s[c][1][0], s[c][1][1]), fmaxf(s[c][1][2], s[c][1][3]));
      float t2 = fmaxf(fmaxf(s[c][2][0], s[c][2][1]), fmaxf(s[c][2][2], s[c][2][3]));
      float t3 = fmaxf(fmaxf(s[c][3][0], s[c][3][1]), fmaxf(s[c][3][2], s[c][3][3]));
      float tm = fmaxf(fmaxf(t0, t1), fmaxf(t2, t3));
      tm = fmaxf(tm, __shfl_xor(tm, 16));
      tm = fmaxf(tm, __shfl_xor(tm, 32));
      if (!__all(tm <= m[c] + 8.0f)) {      // wave-uniform branch
        float mn = fmaxf(m[c], tm);
        float al = __builtin_amdgcn_exp2f(m[c] - mn);
        lsum[c] *= al;
#pragma unroll
        for (int fd = 0; fd < 4; ++fd) o[fd][c] *= al;
        m[c] = mn;
      }
      float r0 = 0.f, r1 = 0.f, r2 = 0.f, r3 = 0.f;
#pragma unroll
      for (int fr = 0; fr < 4; ++fr) {
        float p0 = __builtin_amdgcn_exp2f(s[c][fr][0] - m[c]);
        float p1 = __builtin_amdgcn_exp2f(s[c][fr][1] - m[c]);
        float p2 = __builtin_amdgcn_exp2f(s[c][fr][2] - m[c]);
        float p3 = __builtin_amdgcn_exp2f(s[c][fr][3] - m[c]);
        s[c][fr][0] = p0; s[c][fr][1] = p1; s[c][fr][2] = p2; s[c][fr][3] = p3;
        r0 += p0; r1 += p1; r2 += p2; r3 += p3;
      }
      lsum[c] += (r0 + r1) + (r2 + r3);
    }

    // pack P -> in-register PV B-fragments (V key-permuted to match)
    short8 pf[2][2];
#pragma unroll
    for (int c = 0; c < 2; ++c) {
      union { short8 v; u32 u[4]; } pu0, pu1;
      pu0.u[0] = cvtpk(s[c][0][0], s[c][0][1]);
      pu0.u[1] = cvtpk(s[c][0][2], s[c][0][3]);
      pu0.u[2] = cvtpk(s[c][1][0], s[c][1][1]);
      pu0.u[3] = cvtpk(s[c][1][2], s[c][1][3]);
      pu1.u[0] = cvtpk(s[c][2][0], s[c][2][1]);
      pu1.u[1] = cvtpk(s[c][2][2], s[c][2][3]);
      pu1.u[2] = cvtpk(s[c][3][0], s[c][3][1]);
      pu1.u[3] = cvtpk(s[c][3][2], s[c][3][3]);
      pf[c][0] = pu0.v;
      pf[c][1] = pu1.v;
    }

    // PV: O^T += V^T x P^T
    __builtin_amdgcn_s_setprio(1);
#pragma unroll
    for (int ks2 = 0; ks2 < 2; ++ks2) {
      short8 vf[4];
#pragma unroll
      for (int fd = 0; fd < 4; ++fd)
        vf[fd] = *(const short8*)(Vtile + (fd * 16 + ll) * 128 + ((ks2 * 64 + g * 16) ^ swz));
#pragma unroll
      for (int fd = 0; fd < 4; ++fd)
#pragma unroll
        for (int c = 0; c < 2; ++c)
          o[fd][c] = MFMA16(vf[fd], pf[c][ks2], o[fd][c]);
    }
    __builtin_amdgcn_s_setprio(0);
    cur ^= 1;
  }

  // final cross-lane lsum reduce, normalize + write attn_out[n][h*64+d] bf16
#pragma unroll
  for (int c = 0; c < 2; ++c) {
    float ls = lsum[c];
    ls += __shfl_xor(ls, 16);
    ls += __shfl_xor(ls, 32);
    float inv = 1.f / ls;
    int n = q0 + c * 16 + ll;
#pragma unroll
    for (int fd = 0; fd < 4; ++fd) {
      uint2 pk;
      pk.x = cvtpk(o[fd][c][0] * inv, o[fd][c][1] * inv);
      pk.y = cvtpk(o[fd][c][2] * inv, o[fd][c][3] * inv);
      *(uint2*)&aout[(size_t)n * 1024 + h * 64 + fd * 16 + g * 4] = pk;
    }
  }
}

extern "C" void kernel_launch(void* const* d_in, const int* in_sizes, int n_in,
                              void* d_out, int out_size, void* d_ws, size_t ws_size,
                              hipStream_t stream) {
  const float* x    = (const float*)d_in[0];
  const float* Wqkv = (const float*)d_in[1];
  const float* bqkv = (const float*)d_in[2];
  const float* Wout = (const float*)d_in[3];
  const float* bout = (const float*)d_in[4];
  float* out = (float*)d_out;

  // d_ws usage: 24 MB total (defensive — ws_size is harness-chosen).
  u16* ws    = (u16*)d_ws;
  u16* xb    = ws;                            // 4M u16 = 8 MB (reused as aout)
  u16* wqkvT = xb + (size_t)4096 * 1024;      // 6 MB
  u16* woutT = wqkvT + (size_t)3072 * 1024;   // 2 MB
  u16* Vt    = woutT + (size_t)1024 * 1024;   // 8 MB
  u16* aout  = xb;                            // alias: xb dead after gemm<0>

  // Q and K live in d_out (16 MB fp32 buffer; holds exactly 2 x 8 MB bf16).
  // Both are dead before gemm<1> rewrites d_out in full.
  u16* Qb = (u16*)d_out;                      // 8 MB
  u16* Kb = Qb + (size_t)16 * 4096 * 64;      // 8 MB

  cvt_x<<<2048, 256, 0, stream>>>(x, xb);
  tr_cvt<<<dim3(48, 16), 256, 0, stream>>>(Wqkv, wqkvT, 1024, 3072);
  tr_cvt<<<dim3(16, 16), 256, 0, stream>>>(Wout, woutT, 1024, 1024);
  gemm_bt<0><<<dim3(32, 24), 256, 0, stream>>>(xb, wqkvT, 1024, bqkv, nullptr, Qb, Kb, Vt);
  attn_kernel<<<512, 256, 0, stream>>>(Qb, Kb, Vt, aout);
  gemm_bt<1><<<dim3(32, 8), 256, 0, stream>>>(aout, woutT, 1024, bout, out,
                                              nullptr, nullptr, nullptr);
}